// Round 15
// baseline (110.288 us; speedup 1.0000x reference)
//
#include <hip/hip_runtime.h>

#define LN_EPS 1e-5f

typedef _Float16 f16x4 __attribute__((ext_vector_type(4)));
typedef float f32x4 __attribute__((ext_vector_type(4)));
typedef unsigned int u32;
typedef u32 u32x2 __attribute__((ext_vector_type(2)));

#if defined(__HIP_DEVICE_COMPILE__)
#  if __has_builtin(__builtin_amdgcn_mfma_f32_16x16x16f16)
#    define MFMA16(a, b, c) __builtin_amdgcn_mfma_f32_16x16x16f16(a, b, c, 0, 0, 0)
#  elif __has_builtin(__builtin_amdgcn_mfma_f32_16x16x16_f16)
#    define MFMA16(a, b, c) __builtin_amdgcn_mfma_f32_16x16x16_f16(a, b, c, 0, 0, 0)
#  else
#    error "no 16x16x16 f16 mfma builtin on device"
#  endif
#else
#  define MFMA16(a, b, c) (c)   /* host pass: parse-only dummy, never executed */
#endif

__device__ __forceinline__ float fast_rcp(float x) { return __builtin_amdgcn_rcpf(x); }

__device__ __forceinline__ u32 pk2(float a, float b) {
    return __builtin_bit_cast(u32, __builtin_amdgcn_cvt_pkrtz(a, b));
}
__device__ __forceinline__ f16x4 mk4(float a, float b, float c, float d) {
    u32x2 t = {pk2(a, b), pk2(c, d)};
    return __builtin_bit_cast(f16x4, t);
}

// Unclamped silu: overflow self-corrects (exp->inf -> rcp->0 -> 0, exact limit).
__device__ __forceinline__ float silu_f(float a) {
    return a * fast_rcp(1.0f + __expf(-a));
}
// Plain sigmoid (gate path: tanh folded into weights as 2*sigma-1).
__device__ __forceinline__ float sig_f(float c) {
    return fast_rcp(1.0f + __expf(-c));
}
__device__ __forceinline__ float softplus_f(float x) {
    float e = __expf(-fabsf(x));
    return fmaxf(x, 0.0f) + __logf(1.0f + e);
}

// ======================= d_ws layout (dword units) =======================
// [0, 1536):   A fragments, 12 mfma x 64 lanes x 2 dwords (f16x4 each)
//              0:g1 (2*gw1)  1:g2 (2*gw2, logits replicated)  2:e1L1a
//              3:e1L1b(+murow@8) 4:e1L2a 5:e1L2b 6:e2L1a 7:e2L1b(+murow@8)
//              8:e2L2a 9:e2L2b 10:trunk 11:heads
// [1536,4096): bias C-in fragments, 10 x 64 x 4 f32
//              bf0 = 2*gb1; bf1 = gb2 - colsum(gw2), replicated
// [4096,6144): LN norm fragments, (expert*4+w) x 64 x 4 f32
// =========================================================================

__device__ __forceinline__ float aval(int m, int row, int k,
                                      const float* gw1, const float* gw2,
                                      const float* e1w1, const float* e1w2,
                                      const float* e2w1, const float* e2w2,
                                      const float* tw, const float* sw, const float* hw) {
    switch (m) {
        case 0:  return (row < 8) ? 2.0f * gw1[k * 8 + row] : 0.0f;
        case 1:  return ((row & 3) < 2 && k < 8) ? 2.0f * gw2[k * 2 + (row & 3)] : 0.0f;
        case 2:  return e1w1[k * 24 + row];
        case 3: {
            if (row < 8) return e1w1[k * 24 + 16 + row];
            if (row == 8) {
                float t = 0.0f;
                for (int j = 0; j < 24; ++j) t += e1w1[k * 24 + j];
                return t * (1.0f / 24.0f);
            }
            return 0.0f;
        }
        case 4:  return e1w2[k * 16 + row];
        case 5:  return (k < 8) ? e1w2[(16 + k) * 16 + row] : 0.0f;
        case 6:  return e2w1[k * 24 + row];
        case 7: {
            if (row < 8) return e2w1[k * 24 + 16 + row];
            if (row == 8) {
                float t = 0.0f;
                for (int j = 0; j < 24; ++j) t += e2w1[k * 24 + j];
                return t * (1.0f / 24.0f);
            }
            return 0.0f;
        }
        case 8:  return e2w2[k * 16 + row];
        case 9:  return (k < 8) ? e2w2[(16 + k) * 16 + row] : 0.0f;
        case 10: return tw[k * 16 + row];
        default:
            if (row == 0) return sw[k];
            if (row == 1) return hw[2 * k + 0];
            if (row == 2) return hw[2 * k + 1];
            return 0.0f;
    }
}

__device__ __forceinline__ float bval(int bf, int row,
                                      const float* gb1, const float* gb2, const float* gw2,
                                      const float* e1b1, const float* e1b2,
                                      const float* e2b1, const float* e2b2,
                                      const float* tb, const float* sb, const float* hb) {
    switch (bf) {
        case 0:  return (row < 8) ? 2.0f * gb1[row] : 0.0f;
        case 1: {
            int j = row & 3;
            if (j >= 2) return 0.0f;
            float cs = 0.0f;
            for (int k = 0; k < 8; ++k) cs += gw2[k * 2 + j];
            return gb2[j] - cs;     // l = sum(2*w2*sigma) + (b2 - colsum(w2))
        }
        case 2:  return e1b1[row];
        case 3: {
            if (row < 8) return e1b1[16 + row];
            if (row == 8) {
                float t = 0.0f;
                for (int j = 0; j < 24; ++j) t += e1b1[j];
                return t * (1.0f / 24.0f);
            }
            return 0.0f;
        }
        case 4:  return e1b2[row];
        case 5:  return e2b1[row];
        case 6: {
            if (row < 8) return e2b1[16 + row];
            if (row == 8) {
                float t = 0.0f;
                for (int j = 0; j < 24; ++j) t += e2b1[j];
                return t * (1.0f / 24.0f);
            }
            return 0.0f;
        }
        case 7:  return e2b2[row];
        case 8:  return tb[row];
        default:
            if (row == 0) return sb[0];
            if (row == 1) return hb[0];
            if (row == 2) return hb[1];
            return 0.0f;
    }
}

__global__ void pack_frags(const float* __restrict__ gw1, const float* __restrict__ gb1,
                           const float* __restrict__ gw2, const float* __restrict__ gb2,
                           const float* __restrict__ e1w1, const float* __restrict__ e1b1,
                           const float* __restrict__ e1g, const float* __restrict__ e1bn,
                           const float* __restrict__ e1w2, const float* __restrict__ e1b2,
                           const float* __restrict__ e2w1, const float* __restrict__ e2b1,
                           const float* __restrict__ e2g, const float* __restrict__ e2bn,
                           const float* __restrict__ e2w2, const float* __restrict__ e2b2,
                           const float* __restrict__ tw, const float* __restrict__ tb,
                           const float* __restrict__ sw, const float* __restrict__ sb,
                           const float* __restrict__ hw, const float* __restrict__ hb,
                           u32* __restrict__ ws) {
    int t = blockIdx.x * blockDim.x + threadIdx.x;
    if (t < 1536) {
        int m = t >> 7, rem = t & 127, lane = rem >> 1, d = rem & 1;
        int row = lane & 15, k0 = (lane >> 4) * 4 + 2 * d;
        float v0 = aval(m, row, k0,     gw1, gw2, e1w1, e1w2, e2w1, e2w2, tw, sw, hw);
        float v1 = aval(m, row, k0 + 1, gw1, gw2, e1w1, e1w2, e2w1, e2w2, tw, sw, hw);
        ws[t] = pk2(v0, v1);
    } else if (t < 4096) {
        int f = t - 1536;
        int bf = f >> 8, rem = f & 255, lane = rem >> 2, r = rem & 3;
        int row = (lane >> 4) * 4 + r;
        float v = bval(bf, row, gb1, gb2, gw2, e1b1, e1b2, e2b1, e2b2, tb, sb, hb);
        ((float*)ws)[t] = v;
    } else if (t < 6144) {
        int f = t - 4096;
        int nf = f >> 8, rem = f & 255, lane = rem >> 2, r = rem & 3;
        int e = nf >> 2, w = nf & 3, g_ = lane >> 4;
        const float* ge = e ? e2g : e1g;
        const float* bne = e ? e2bn : e1bn;
        float v;
        if (w < 2) {
            int feat = g_ * 4 + r;
            v = (w == 0) ? ge[feat] : bne[feat];
        } else {
            int feat = 16 + g_ * 4 + r;
            v = (g_ < 2) ? ((w == 2) ? ge[feat] : bne[feat]) : 0.0f;
        }
        ((float*)ws)[t] = v;
    }
}

// GUARD=true: handle nrows not divisible by 64 (clamped loads, guarded stores).
template <bool GUARD>
__global__ __launch_bounds__(256) void moe_mfma_kernel(const float* __restrict__ x,
                                                       const u32* __restrict__ ws,
                                                       float* __restrict__ out, int nrows) {
    __shared__ u32 lds[6144];
    for (int i = threadIdx.x; i < 6144; i += 256) lds[i] = ws[i];
    __syncthreads();

    int lane = threadIdx.x & 63;
    int g = lane >> 4, s = lane & 15;
    float mask0 = (g == 2) ? 0.0f : 1.0f;   // exclude mu-row from variance
    int wid = (blockIdx.x * blockDim.x + threadIdx.x) >> 6;
    int nw = (gridDim.x * blockDim.x) >> 6;

    auto LA  = [&](int m)  -> f16x4 { return *(const f16x4*)&lds[m * 128 + lane * 2]; };
    auto LB  = [&](int bf) -> f32x4 { return *(const f32x4*)&lds[1536 + bf * 256 + lane * 4]; };
    auto LNF = [&](int nf) -> f32x4 { return *(const f32x4*)&lds[4096 + nf * 256 + lane * 4]; };

    int ntiles = (nrows + 15) >> 4;
    int nclamp = nrows - 1;

    auto loadx = [&](int tile) -> f32x4 {
        int r = tile * 16 + s;
        if (GUARD) r = r < nrows ? r : nclamp;
        return *(const f32x4*)(x + (size_t)r * 16 + g * 4);
    };

    // Four-tile expert: every fragment read amortized 4 ways.
    auto expert4 = [&](bool FIRST, int mA1a, int mA1b, int mA2a, int mA2b,
                       int bf1a, int bf1b, int bf2, int nf,
                       const f16x4 Bx[4], const float sc[4], f32x4 h[4]) {
        f16x4 A1a = LA(mA1a), A1b = LA(mA1b);
        f32x4 b1a = LB(bf1a), b1b = LB(bf1b);
        f32x4 C1[4], C2[4];
#pragma unroll
        for (int t = 0; t < 4; ++t) {
            C1[t] = MFMA16(A1a, Bx[t], b1a);
            C2[t] = MFMA16(A1b, Bx[t], b1b);
        }
        float mu[4], rstd[4];
#pragma unroll
        for (int t = 0; t < 4; ++t) mu[t] = __shfl(C2[t][0], 32 + s, 64);
#pragma unroll
        for (int t = 0; t < 4; ++t) {
            float E2 = 0.0f;
#pragma unroll
            for (int i = 0; i < 4; ++i) E2 = fmaf(C1[t][i], C1[t][i], E2);
            E2 = fmaf(C2[t][0] * mask0, C2[t][0], E2);
#pragma unroll
            for (int i = 1; i < 4; ++i) E2 = fmaf(C2[t][i], C2[t][i], E2);
            E2 += __shfl_xor(E2, 16);
            E2 += __shfl_xor(E2, 32);
            rstd[t] = rsqrtf(fmaf(E2, 1.0f / 24.0f, -mu[t] * mu[t]) + LN_EPS);
        }
        f32x4 gc1 = LNF(nf + 0), bc1 = LNF(nf + 1), gc2 = LNF(nf + 2), bc2 = LNF(nf + 3);
        f16x4 B1[4], B2[4];
#pragma unroll
        for (int t = 0; t < 4; ++t) {
            float sv[8];
#pragma unroll
            for (int i = 0; i < 4; ++i) {
                sv[i]     = silu_f(fmaf((C1[t][i] - mu[t]) * rstd[t], gc1[i], bc1[i]));
                sv[4 + i] = silu_f(fmaf((C2[t][i] - mu[t]) * rstd[t], gc2[i], bc2[i]));
            }
            B1[t] = mk4(sv[0], sv[1], sv[2], sv[3]);
            B2[t] = mk4(sv[4], sv[5], sv[6], sv[7]);
        }
        f16x4 A2a = LA(mA2a), A2b = LA(mA2b);
        f32x4 b2 = LB(bf2);
#pragma unroll
        for (int t = 0; t < 4; ++t) {
            f32x4 O = MFMA16(A2a, B1[t], b2);
            O = MFMA16(A2b, B2[t], O);
#pragma unroll
            for (int i = 0; i < 4; ++i) {
                float p = silu_f(O[i]);
                if (FIRST) h[t][i] = sc[t] * p;
                else       h[t][i] = fmaf(sc[t], p, h[t][i]);
            }
        }
    };

    int tq0 = 4 * wid;
    int stride = 4 * nw;
    f32x4 xv[4];
    if (tq0 < ntiles) {
#pragma unroll
        for (int t = 0; t < 4; ++t) {
            int tt = tq0 + t;
            if (GUARD && tt >= ntiles) tt = ntiles - 1;
            xv[t] = loadx(tt);
        }
    }

    for (int tq = tq0; tq < ntiles; tq += stride) {
        // ---- prefetch next quad (uniform clamp, OOB-safe) ----
        f32x4 xn[4];
        {
            int tnq = tq + stride;
            if (tnq + 3 >= ntiles) tnq = tq;   // last iteration: re-read current (discarded)
#pragma unroll
            for (int t = 0; t < 4; ++t) xn[t] = loadx(tnq + t);
        }

        f16x4 Bx[4];
#pragma unroll
        for (int t = 0; t < 4; ++t) Bx[t] = mk4(xv[t][0], xv[t][1], xv[t][2], xv[t][3]);

        // ---- gate: weights pre-scaled so MFMA gives 2*preact; sigma feeds folded g2 ----
        f16x4 Ag1 = LA(0), Ag2 = LA(1);
        f32x4 Bg1 = LB(0), Bg2 = LB(1);
        float w0[4], w1[4];
#pragma unroll
        for (int t = 0; t < 4; ++t) {
            f32x4 Cg = MFMA16(Ag1, Bx[t], Bg1);
            f16x4 Bt = mk4(sig_f(Cg[0]), sig_f(Cg[1]), sig_f(Cg[2]), sig_f(Cg[3]));
            f32x4 Cl = MFMA16(Ag2, Bt, Bg2);
            w0[t] = fast_rcp(1.0f + __expf(Cl[1] - Cl[0]));   // sigmoid(l0 - l1)
            w1[t] = 1.0f - w0[t];
        }

        // ---- experts ----
        f32x4 h[4];
        expert4(true,  2, 3, 4, 5, 2, 3, 4, 0, Bx, w0, h);
        expert4(false, 6, 7, 8, 9, 5, 6, 7, 4, Bx, w1, h);

        // ---- trunk + heads ----
        f16x4 Atr = LA(10), Ahd = LA(11);
        f32x4 Btr = LB(8), Bhd = LB(9);
#pragma unroll
        for (int t = 0; t < 4; ++t) {
            f16x4 Bh = mk4(h[t][0], h[t][1], h[t][2], h[t][3]);
            f32x4 Ct = MFMA16(Atr, Bh, Btr);
            f16x4 Bu = mk4(silu_f(Ct[0]), silu_f(Ct[1]), silu_f(Ct[2]), silu_f(Ct[3]));
            f32x4 Ch = MFMA16(Ahd, Bu, Bhd);
            int r = (tq + t) * 16 + s;
            bool ok = GUARD ? (g == 0 && r < nrows) : (g == 0);
            if (ok) {
                float yld = Ch[1] - softplus_f(Ch[2]);
                size_t o = (size_t)r * 3;
                out[o + 0] = Ch[0];
                out[o + 1] = Ch[1];
                out[o + 2] = yld;
            }
        }

#pragma unroll
        for (int t = 0; t < 4; ++t) xv[t] = xn[t];
    }
}

extern "C" void kernel_launch(void* const* d_in, const int* in_sizes, int n_in,
                              void* d_out, int out_size, void* d_ws, size_t ws_size,
                              hipStream_t stream) {
    const float* x    = (const float*)d_in[0];
    const float* gw1  = (const float*)d_in[1];
    const float* gb1  = (const float*)d_in[2];
    const float* gw2  = (const float*)d_in[3];
    const float* gb2  = (const float*)d_in[4];
    const float* e1w1 = (const float*)d_in[5];
    const float* e1b1 = (const float*)d_in[6];
    const float* e1g  = (const float*)d_in[7];
    const float* e1bn = (const float*)d_in[8];
    const float* e1w2 = (const float*)d_in[9];
    const float* e1b2 = (const float*)d_in[10];
    const float* e2w1 = (const float*)d_in[11];
    const float* e2b1 = (const float*)d_in[12];
    const float* e2g  = (const float*)d_in[13];
    const float* e2bn = (const float*)d_in[14];
    const float* e2w2 = (const float*)d_in[15];
    const float* e2b2 = (const float*)d_in[16];
    const float* tw   = (const float*)d_in[17];
    const float* tb   = (const float*)d_in[18];
    const float* sw   = (const float*)d_in[19];
    const float* sb   = (const float*)d_in[20];
    const float* hw   = (const float*)d_in[21];
    const float* hb   = (const float*)d_in[22];
    float* out = (float*)d_out;
    u32* ws = (u32*)d_ws;

    pack_frags<<<24, 256, 0, stream>>>(gw1, gb1, gw2, gb2,
                                       e1w1, e1b1, e1g, e1bn, e1w2, e1b2,
                                       e2w1, e2b1, e2g, e2bn, e2w2, e2b2,
                                       tw, tb, sw, sb, hw, hb, ws);

    int nrows = in_sizes[0] / 16;
    if (nrows % 64 == 0) {
        moe_mfma_kernel<false><<<2048, 256, 0, stream>>>(x, ws, out, nrows);
    } else {
        moe_mfma_kernel<true><<<2048, 256, 0, stream>>>(x, ws, out, nrows);
    }
}

// Round 16
// 100.289 us; speedup vs baseline: 1.0997x; 1.0997x over previous
//
#include <hip/hip_runtime.h>

#define LN_EPS 1e-5f

typedef _Float16 f16x4 __attribute__((ext_vector_type(4)));
typedef float f32x4 __attribute__((ext_vector_type(4)));
typedef unsigned int u32;
typedef u32 u32x2 __attribute__((ext_vector_type(2)));

#if defined(__HIP_DEVICE_COMPILE__)
#  if __has_builtin(__builtin_amdgcn_mfma_f32_16x16x16f16)
#    define MFMA16(a, b, c) __builtin_amdgcn_mfma_f32_16x16x16f16(a, b, c, 0, 0, 0)
#  elif __has_builtin(__builtin_amdgcn_mfma_f32_16x16x16_f16)
#    define MFMA16(a, b, c) __builtin_amdgcn_mfma_f32_16x16x16_f16(a, b, c, 0, 0, 0)
#  else
#    error "no 16x16x16 f16 mfma builtin on device"
#  endif
#else
#  define MFMA16(a, b, c) (c)   /* host pass: parse-only dummy, never executed */
#endif

__device__ __forceinline__ float fast_rcp(float x) { return __builtin_amdgcn_rcpf(x); }

__device__ __forceinline__ u32 pk2(float a, float b) {
    return __builtin_bit_cast(u32, __builtin_amdgcn_cvt_pkrtz(a, b));
}
__device__ __forceinline__ f16x4 mk4(float a, float b, float c, float d) {
    u32x2 t = {pk2(a, b), pk2(c, d)};
    return __builtin_bit_cast(f16x4, t);
}

// Unclamped silu: overflow self-corrects (exp->inf -> rcp->0 -> 0, exact limit).
__device__ __forceinline__ float silu_f(float a) {
    return a * fast_rcp(1.0f + __expf(-a));
}
// Plain sigmoid (gate path: tanh folded into weights as 2*sigma-1).
__device__ __forceinline__ float sig_f(float c) {
    return fast_rcp(1.0f + __expf(-c));
}
__device__ __forceinline__ float softplus_f(float x) {
    float e = __expf(-fabsf(x));
    return fmaxf(x, 0.0f) + __logf(1.0f + e);
}

// ======================= d_ws layout (dword units) =======================
// [0, 1536):   A fragments, 12 mfma x 64 lanes x 2 dwords (f16x4 each)
//              0:g1 (2*gw1)  1:g2 (2*gw2, logits replicated)  2:e1L1a
//              3:e1L1b(+murow@8) 4:e1L2a 5:e1L2b 6:e2L1a 7:e2L1b(+murow@8)
//              8:e2L2a 9:e2L2b 10:trunk 11:heads
// [1536,4096): bias C-in fragments, 10 x 64 x 4 f32
//              bf0 = 2*gb1; bf1 = gb2 - colsum(gw2), replicated
// [4096,6144): LN norm fragments, (expert*4+w) x 64 x 4 f32
// =========================================================================

__device__ __forceinline__ float aval(int m, int row, int k,
                                      const float* gw1, const float* gw2,
                                      const float* e1w1, const float* e1w2,
                                      const float* e2w1, const float* e2w2,
                                      const float* tw, const float* sw, const float* hw) {
    switch (m) {
        case 0:  return (row < 8) ? 2.0f * gw1[k * 8 + row] : 0.0f;
        case 1:  return ((row & 3) < 2 && k < 8) ? 2.0f * gw2[k * 2 + (row & 3)] : 0.0f;
        case 2:  return e1w1[k * 24 + row];
        case 3: {
            if (row < 8) return e1w1[k * 24 + 16 + row];
            if (row == 8) {
                float t = 0.0f;
                for (int j = 0; j < 24; ++j) t += e1w1[k * 24 + j];
                return t * (1.0f / 24.0f);
            }
            return 0.0f;
        }
        case 4:  return e1w2[k * 16 + row];
        case 5:  return (k < 8) ? e1w2[(16 + k) * 16 + row] : 0.0f;
        case 6:  return e2w1[k * 24 + row];
        case 7: {
            if (row < 8) return e2w1[k * 24 + 16 + row];
            if (row == 8) {
                float t = 0.0f;
                for (int j = 0; j < 24; ++j) t += e2w1[k * 24 + j];
                return t * (1.0f / 24.0f);
            }
            return 0.0f;
        }
        case 8:  return e2w2[k * 16 + row];
        case 9:  return (k < 8) ? e2w2[(16 + k) * 16 + row] : 0.0f;
        case 10: return tw[k * 16 + row];
        default:
            if (row == 0) return sw[k];
            if (row == 1) return hw[2 * k + 0];
            if (row == 2) return hw[2 * k + 1];
            return 0.0f;
    }
}

__device__ __forceinline__ float bval(int bf, int row,
                                      const float* gb1, const float* gb2, const float* gw2,
                                      const float* e1b1, const float* e1b2,
                                      const float* e2b1, const float* e2b2,
                                      const float* tb, const float* sb, const float* hb) {
    switch (bf) {
        case 0:  return (row < 8) ? 2.0f * gb1[row] : 0.0f;
        case 1: {
            int j = row & 3;
            if (j >= 2) return 0.0f;
            float cs = 0.0f;
            for (int k = 0; k < 8; ++k) cs += gw2[k * 2 + j];
            return gb2[j] - cs;     // l = sum(2*w2*sigma) + (b2 - colsum(w2))
        }
        case 2:  return e1b1[row];
        case 3: {
            if (row < 8) return e1b1[16 + row];
            if (row == 8) {
                float t = 0.0f;
                for (int j = 0; j < 24; ++j) t += e1b1[j];
                return t * (1.0f / 24.0f);
            }
            return 0.0f;
        }
        case 4:  return e1b2[row];
        case 5:  return e2b1[row];
        case 6: {
            if (row < 8) return e2b1[16 + row];
            if (row == 8) {
                float t = 0.0f;
                for (int j = 0; j < 24; ++j) t += e2b1[j];
                return t * (1.0f / 24.0f);
            }
            return 0.0f;
        }
        case 7:  return e2b2[row];
        case 8:  return tb[row];
        default:
            if (row == 0) return sb[0];
            if (row == 1) return hb[0];
            if (row == 2) return hb[1];
            return 0.0f;
    }
}

__global__ void pack_frags(const float* __restrict__ gw1, const float* __restrict__ gb1,
                           const float* __restrict__ gw2, const float* __restrict__ gb2,
                           const float* __restrict__ e1w1, const float* __restrict__ e1b1,
                           const float* __restrict__ e1g, const float* __restrict__ e1bn,
                           const float* __restrict__ e1w2, const float* __restrict__ e1b2,
                           const float* __restrict__ e2w1, const float* __restrict__ e2b1,
                           const float* __restrict__ e2g, const float* __restrict__ e2bn,
                           const float* __restrict__ e2w2, const float* __restrict__ e2b2,
                           const float* __restrict__ tw, const float* __restrict__ tb,
                           const float* __restrict__ sw, const float* __restrict__ sb,
                           const float* __restrict__ hw, const float* __restrict__ hb,
                           u32* __restrict__ ws) {
    int t = blockIdx.x * blockDim.x + threadIdx.x;
    if (t < 1536) {
        int m = t >> 7, rem = t & 127, lane = rem >> 1, d = rem & 1;
        int row = lane & 15, k0 = (lane >> 4) * 4 + 2 * d;
        float v0 = aval(m, row, k0,     gw1, gw2, e1w1, e1w2, e2w1, e2w2, tw, sw, hw);
        float v1 = aval(m, row, k0 + 1, gw1, gw2, e1w1, e1w2, e2w1, e2w2, tw, sw, hw);
        ws[t] = pk2(v0, v1);
    } else if (t < 4096) {
        int f = t - 1536;
        int bf = f >> 8, rem = f & 255, lane = rem >> 2, r = rem & 3;
        int row = (lane >> 4) * 4 + r;
        float v = bval(bf, row, gb1, gb2, gw2, e1b1, e1b2, e2b1, e2b2, tb, sb, hb);
        ((float*)ws)[t] = v;
    } else if (t < 6144) {
        int f = t - 4096;
        int nf = f >> 8, rem = f & 255, lane = rem >> 2, r = rem & 3;
        int e = nf >> 2, w = nf & 3, g_ = lane >> 4;
        const float* ge = e ? e2g : e1g;
        const float* bne = e ? e2bn : e1bn;
        float v;
        if (w < 2) {
            int feat = g_ * 4 + r;
            v = (w == 0) ? ge[feat] : bne[feat];
        } else {
            int feat = 16 + g_ * 4 + r;
            v = (g_ < 2) ? ((w == 2) ? ge[feat] : bne[feat]) : 0.0f;
        }
        ((float*)ws)[t] = v;
    }
}

// GUARD=false requires nrows % 32 == 0 (2 tiles/wave/iter, even ntiles).
template <bool GUARD>
__global__ __launch_bounds__(256) void moe_mfma_kernel(const float* __restrict__ x,
                                                       const u32* __restrict__ ws,
                                                       float* __restrict__ out, int nrows) {
    __shared__ u32 lds[6144];
    for (int i = threadIdx.x; i < 6144; i += 256) lds[i] = ws[i];
    __syncthreads();

    int lane = threadIdx.x & 63;
    int g = lane >> 4, s = lane & 15;
    float mask0 = (g == 2) ? 0.0f : 1.0f;   // exclude mu-row from variance
    int wid = (blockIdx.x * blockDim.x + threadIdx.x) >> 6;
    int nw = (gridDim.x * blockDim.x) >> 6;

    auto LA  = [&](int m)  -> f16x4 { return *(const f16x4*)&lds[m * 128 + lane * 2]; };
    auto LB  = [&](int bf) -> f32x4 { return *(const f32x4*)&lds[1536 + bf * 256 + lane * 4]; };
    auto LNF = [&](int nf) -> f32x4 { return *(const f32x4*)&lds[4096 + nf * 256 + lane * 4]; };

    int ntiles = (nrows + 15) >> 4;
    int nclamp = nrows - 1;

    auto loadx = [&](int tile) -> f32x4 {
        int r = tile * 16 + s;
        if (GUARD) r = r < nrows ? r : nclamp;
        return *(const f32x4*)(x + (size_t)r * 16 + g * 4);
    };

    auto expert2 = [&](bool FIRST, int mA1a, int mA1b, int mA2a, int mA2b,
                       int bf1a, int bf1b, int bf2, int nf,
                       f16x4 Bx0, f16x4 Bx1, float sc0, float sc1,
                       f32x4& h0, f32x4& h1) {
        f16x4 A1a = LA(mA1a), A1b = LA(mA1b);
        f32x4 b1a = LB(bf1a), b1b = LB(bf1b);
        f32x4 C1_0 = MFMA16(A1a, Bx0, b1a);
        f32x4 C1_1 = MFMA16(A1a, Bx1, b1a);
        f32x4 C2_0 = MFMA16(A1b, Bx0, b1b);
        f32x4 C2_1 = MFMA16(A1b, Bx1, b1b);

        float mu0 = __shfl(C2_0[0], 32 + s, 64);
        float mu1 = __shfl(C2_1[0], 32 + s, 64);

        float E20 = 0.0f, E21 = 0.0f;
#pragma unroll
        for (int i = 0; i < 4; ++i) {
            E20 = fmaf(C1_0[i], C1_0[i], E20);
            E21 = fmaf(C1_1[i], C1_1[i], E21);
        }
        E20 = fmaf(C2_0[0] * mask0, C2_0[0], E20);
        E21 = fmaf(C2_1[0] * mask0, C2_1[0], E21);
#pragma unroll
        for (int i = 1; i < 4; ++i) {
            E20 = fmaf(C2_0[i], C2_0[i], E20);
            E21 = fmaf(C2_1[i], C2_1[i], E21);
        }
        E20 += __shfl_xor(E20, 16); E20 += __shfl_xor(E20, 32);
        E21 += __shfl_xor(E21, 16); E21 += __shfl_xor(E21, 32);
        float rstd0 = rsqrtf(fmaf(E20, 1.0f / 24.0f, -mu0 * mu0) + LN_EPS);
        float rstd1 = rsqrtf(fmaf(E21, 1.0f / 24.0f, -mu1 * mu1) + LN_EPS);

        f32x4 gc1 = LNF(nf + 0), bc1 = LNF(nf + 1), gc2 = LNF(nf + 2), bc2 = LNF(nf + 3);
        float sv0[8], sv1[8];
#pragma unroll
        for (int i = 0; i < 4; ++i) {
            sv0[i]     = silu_f(fmaf((C1_0[i] - mu0) * rstd0, gc1[i], bc1[i]));
            sv1[i]     = silu_f(fmaf((C1_1[i] - mu1) * rstd1, gc1[i], bc1[i]));
            sv0[4 + i] = silu_f(fmaf((C2_0[i] - mu0) * rstd0, gc2[i], bc2[i]));
            sv1[4 + i] = silu_f(fmaf((C2_1[i] - mu1) * rstd1, gc2[i], bc2[i]));
        }
        f16x4 B1_0 = mk4(sv0[0], sv0[1], sv0[2], sv0[3]);
        f16x4 B2_0 = mk4(sv0[4], sv0[5], sv0[6], sv0[7]);
        f16x4 B1_1 = mk4(sv1[0], sv1[1], sv1[2], sv1[3]);
        f16x4 B2_1 = mk4(sv1[4], sv1[5], sv1[6], sv1[7]);

        f16x4 A2a = LA(mA2a), A2b = LA(mA2b);
        f32x4 b2 = LB(bf2);
        f32x4 O0 = MFMA16(A2a, B1_0, b2);
        f32x4 O1 = MFMA16(A2a, B1_1, b2);
        O0 = MFMA16(A2b, B2_0, O0);
        O1 = MFMA16(A2b, B2_1, O1);

#pragma unroll
        for (int i = 0; i < 4; ++i) {
            float p0 = silu_f(O0[i]);
            float p1 = silu_f(O1[i]);
            if (FIRST) {
                h0[i] = sc0 * p0;
                h1[i] = sc1 * p1;
            } else {
                h0[i] = fmaf(sc0, p0, h0[i]);
                h1[i] = fmaf(sc1, p1, h1[i]);
            }
        }
    };

    int p0 = 2 * wid;
    f32x4 xv0, xv1;
    if (p0 < ntiles) {
        int t1 = (GUARD && p0 + 1 >= ntiles) ? p0 : p0 + 1;
        xv0 = loadx(p0);
        xv1 = loadx(t1);
    }

    for (int tp = p0; tp < ntiles; tp += 2 * nw) {
        int tnp = tp + 2 * nw;
        f32x4 xn0, xn1;
        {
            int t0n = tnp < ntiles ? tnp : tp;
            int t1n = GUARD ? (tnp + 1 < ntiles ? tnp + 1 : t0n)
                            : (tnp < ntiles ? tnp + 1 : tp);
            xn0 = loadx(t0n);
            xn1 = loadx(t1n);
        }

        int r0 = tp * 16 + s;
        int r1 = (tp + 1) * 16 + s;
        f16x4 Bx0 = mk4(xv0[0], xv0[1], xv0[2], xv0[3]);
        f16x4 Bx1 = mk4(xv1[0], xv1[1], xv1[2], xv1[3]);

        // ---- gate: pre-scaled weights, sigma replaces tanh (folded 2*sigma-1) ----
        f32x4 Cg0 = MFMA16(LA(0), Bx0, LB(0));
        f32x4 Cg1 = MFMA16(LA(0), Bx1, LB(0));
        f16x4 Bt0 = mk4(sig_f(Cg0[0]), sig_f(Cg0[1]), sig_f(Cg0[2]), sig_f(Cg0[3]));
        f16x4 Bt1 = mk4(sig_f(Cg1[0]), sig_f(Cg1[1]), sig_f(Cg1[2]), sig_f(Cg1[3]));
        f32x4 Cl0 = MFMA16(LA(1), Bt0, LB(1));
        f32x4 Cl1 = MFMA16(LA(1), Bt1, LB(1));
        float w00 = fast_rcp(1.0f + __expf(Cl0[1] - Cl0[0]));
        float w01 = 1.0f - w00;
        float w10 = fast_rcp(1.0f + __expf(Cl1[1] - Cl1[0]));
        float w11 = 1.0f - w10;

        // ---- experts ----
        f32x4 h0, h1;
        expert2(true,  2, 3, 4, 5, 2, 3, 4, 0, Bx0, Bx1, w00, w10, h0, h1);
        expert2(false, 6, 7, 8, 9, 5, 6, 7, 4, Bx0, Bx1, w01, w11, h0, h1);

        // ---- trunk ----
        f16x4 Bh0 = mk4(h0[0], h0[1], h0[2], h0[3]);
        f16x4 Bh1 = mk4(h1[0], h1[1], h1[2], h1[3]);
        f32x4 Ct0 = MFMA16(LA(10), Bh0, LB(8));
        f32x4 Ct1 = MFMA16(LA(10), Bh1, LB(8));
        f16x4 Bu0 = mk4(silu_f(Ct0[0]), silu_f(Ct0[1]), silu_f(Ct0[2]), silu_f(Ct0[3]));
        f16x4 Bu1 = mk4(silu_f(Ct1[0]), silu_f(Ct1[1]), silu_f(Ct1[2]), silu_f(Ct1[3]));

        // ---- heads ----
        f32x4 Ch0 = MFMA16(LA(11), Bu0, LB(9));
        f32x4 Ch1 = MFMA16(LA(11), Bu1, LB(9));
        if (g == 0) {
            if (!GUARD || r0 < nrows) {
                float yld = Ch0[1] - softplus_f(Ch0[2]);
                size_t o = (size_t)r0 * 3;
                out[o + 0] = Ch0[0];
                out[o + 1] = Ch0[1];
                out[o + 2] = yld;
            }
            if (!GUARD || r1 < nrows) {
                float yld = Ch1[1] - softplus_f(Ch1[2]);
                size_t o = (size_t)r1 * 3;
                out[o + 0] = Ch1[0];
                out[o + 1] = Ch1[1];
                out[o + 2] = yld;
            }
        }

        xv0 = xn0;
        xv1 = xn1;
    }
}

extern "C" void kernel_launch(void* const* d_in, const int* in_sizes, int n_in,
                              void* d_out, int out_size, void* d_ws, size_t ws_size,
                              hipStream_t stream) {
    const float* x    = (const float*)d_in[0];
    const float* gw1  = (const float*)d_in[1];
    const float* gb1  = (const float*)d_in[2];
    const float* gw2  = (const float*)d_in[3];
    const float* gb2  = (const float*)d_in[4];
    const float* e1w1 = (const float*)d_in[5];
    const float* e1b1 = (const float*)d_in[6];
    const float* e1g  = (const float*)d_in[7];
    const float* e1bn = (const float*)d_in[8];
    const float* e1w2 = (const float*)d_in[9];
    const float* e1b2 = (const float*)d_in[10];
    const float* e2w1 = (const float*)d_in[11];
    const float* e2b1 = (const float*)d_in[12];
    const float* e2g  = (const float*)d_in[13];
    const float* e2bn = (const float*)d_in[14];
    const float* e2w2 = (const float*)d_in[15];
    const float* e2b2 = (const float*)d_in[16];
    const float* tw   = (const float*)d_in[17];
    const float* tb   = (const float*)d_in[18];
    const float* sw   = (const float*)d_in[19];
    const float* sb   = (const float*)d_in[20];
    const float* hw   = (const float*)d_in[21];
    const float* hb   = (const float*)d_in[22];
    float* out = (float*)d_out;
    u32* ws = (u32*)d_ws;

    pack_frags<<<24, 256, 0, stream>>>(gw1, gb1, gw2, gb2,
                                       e1w1, e1b1, e1g, e1bn, e1w2, e1b2,
                                       e2w1, e2b1, e2g, e2bn, e2w2, e2b2,
                                       tw, tb, sw, sb, hw, hb, ws);

    int nrows = in_sizes[0] / 16;
    if (nrows % 32 == 0) {
        moe_mfma_kernel<false><<<2048, 256, 0, stream>>>(x, ws, out, nrows);
    } else {
        moe_mfma_kernel<true><<<2048, 256, 0, stream>>>(x, ws, out, nrows);
    }
}